// Round 1
// 1608.775 us; speedup vs baseline: 1.5841x; 1.5841x over previous
//
#include <hip/hip_runtime.h>

#define TOK 4096   // B*S tokens
#define DIM 2048   // D
#define NEXP 8     // E
#define FF 4096    // F
#define MAXROWS 9216   // 2*TOK rows padded to 128-multiples per expert (8192 + 8*128)

typedef short short8 __attribute__((ext_vector_type(8)));
typedef float f32x4 __attribute__((ext_vector_type(4)));

__device__ inline ushort f2bf(float f){
  union { float f; unsigned u; } v; v.f = f;
  return (ushort)((v.u + 0x7fffu + ((v.u >> 16) & 1u)) >> 16);
}

__device__ inline void load_lds16(const void* g, void* l){
  __builtin_amdgcn_global_load_lds((const __attribute__((address_space(1))) void*)g,
                                   (__attribute__((address_space(3))) void*)l, 16, 0, 0);
}

// ---------------- router: logits, softmax top-2, per-expert lists ----------------
__global__ void router_kernel(const float* __restrict__ x, const float* __restrict__ Wg,
                              float* __restrict__ logits, int* __restrict__ counts,
                              int* __restrict__ etok, float* __restrict__ ewt,
                              int* __restrict__ eslot){
  int lane = threadIdx.x & 63;
  int wid  = threadIdx.x >> 6;
  int t = blockIdx.x * 4 + wid;          // one wave per token
  const float* xr = x + (size_t)t * DIM;
  float acc[NEXP];
#pragma unroll
  for (int e = 0; e < NEXP; ++e) acc[e] = 0.f;
#pragma unroll
  for (int c = 0; c < DIM/256; ++c){
    int k = c*256 + lane*4;
    float4 xv = *(const float4*)(xr + k);
#pragma unroll
    for (int e = 0; e < NEXP; ++e){
      float4 wv = *(const float4*)(Wg + e*DIM + k);
      acc[e] += xv.x*wv.x + xv.y*wv.y + xv.z*wv.z + xv.w*wv.w;
    }
  }
#pragma unroll
  for (int e = 0; e < NEXP; ++e){
#pragma unroll
    for (int off = 32; off > 0; off >>= 1) acc[e] += __shfl_xor(acc[e], off, 64);
  }
  if (lane == 0){
#pragma unroll
    for (int e = 0; e < NEXP; ++e) logits[(size_t)t*NEXP + e] = acc[e];
    int i0 = 0;
    for (int e = 1; e < NEXP; ++e) if (acc[e] > acc[i0]) i0 = e;
    int i1 = (i0 == 0) ? 1 : 0;
    for (int e = 0; e < NEXP; ++e) if (e != i0 && acc[e] > acc[i1]) i1 = e;
    float p1 = __expf(acc[i1] - acc[i0]);
    float s = 1.f + p1;
    float w0 = 1.f / s, w1 = p1 / s;
    int pos0 = atomicAdd(&counts[i0], 1);
    etok[i0*TOK + pos0] = (int)((unsigned)t | (i0 < i1 ? 0x80000000u : 0u));
    ewt [i0*TOK + pos0] = w0;
    eslot[t*2 + 0] = (i0 << 16) | pos0;
    int pos1 = atomicAdd(&counts[i1], 1);
    etok[i1*TOK + pos1] = (int)((unsigned)t | (i1 < i0 ? 0x80000000u : 0u));
    ewt [i1*TOK + pos1] = w1;
    eslot[t*2 + 1] = (i1 << 16) | pos1;
  }
}

// ------------- offsets: 128-padded exclusive prefix of counts -------------
__global__ void offsets_kernel(const int* __restrict__ counts, int* __restrict__ offs){
  if (threadIdx.x == 0){
    int o = 0;
    for (int e = 0; e < NEXP; ++e){ offs[e] = o; o += (counts[e] + 127) & ~127; }
    offs[NEXP] = o;
  }
}

// ============================ FUSED (all-expert) PATH ============================

// gather all token-expert pairs into packed Ag (one block per pair, all active)
__global__ void gatherf_kernel(const float* __restrict__ x, const int* __restrict__ offs,
                               const int* __restrict__ eslot, ushort* __restrict__ Ag){
  int p = blockIdx.x;                     // pair index 0..2*TOK
  int t = p >> 1;
  int v = eslot[p];
  int e = v >> 16, pos = v & 0xffff;
  size_t drow = (size_t)offs[e] + pos;
  int c = threadIdx.x;                    // 256 chunks of 8 elems
  const float4* src = (const float4*)(x + (size_t)t*DIM + c*8);
  float4 a = src[0], b = src[1];
  ushort o[8] = { f2bf(a.x), f2bf(a.y), f2bf(a.z), f2bf(a.w),
                  f2bf(b.x), f2bf(b.y), f2bf(b.z), f2bf(b.w) };
  *(short8*)(Ag + drow*DIM + c*8) = *(const short8*)o;
}

// convert ALL experts' weights -> bf16 MFMA-native packed-B 1KB blocks, one launch
__global__ void convwf_kernel(const float* __restrict__ W1, const float* __restrict__ W3,
                              const float* __restrict__ W2, ushort* __restrict__ W1P,
                              ushort* __restrict__ W3P, ushort* __restrict__ W2P){
  const int NB = (DIM/32)*(FF/16);        // 16384 blocks per matrix per expert
  int lane = threadIdx.x & 63;
  int bo = blockIdx.x*4 + (threadIdx.x >> 6);   // < 3*NEXP*NB = 393216
  int mat = bo >> 17;                     // NEXP*NB = 2^17
  int e   = (bo >> 14) & (NEXP-1);        // NB = 2^14
  int blk = bo & (NB-1);
  size_t we = (size_t)DIM*FF;
  const float* src; ushort* dst; int Nst;
  if (mat == 0)      { src = W1 + we*e; dst = W1P + we*e; Nst = FF; }
  else if (mat == 1) { src = W3 + we*e; dst = W3P + we*e; Nst = FF; }
  else               { src = W2 + we*e; dst = W2P + we*e; Nst = DIM; }
  int lg = (mat == 2) ? 7 : 8;            // Nst/16 = 128 or 256
  int kt = blk >> lg;
  int nt = blk & ((1 << lg) - 1);
  int n  = nt*16 + (lane & 15);
  int k0 = kt*32 + ((lane >> 4) << 3);
  ushort o[8];
#pragma unroll
  for (int j = 0; j < 8; ++j) o[j] = f2bf(src[(size_t)(k0+j)*Nst + n]);
  *(short8*)(dst + (size_t)blk*512 + lane*8) = *(const short8*)o;
}

// find expert for a global (packed) m-block via the 9-entry offset table
__device__ inline int find_expert(const int* offs, int r0){
  int e = 0;
#pragma unroll
  for (int i = 1; i < NEXP; ++i) e += (r0 >= offs[i]);
  return e;
}

// GEMM1 fused: h = silu(Ag@W1) * (Ag@W3) over all experts
__global__ __launch_bounds__(256, 2) void gemm1f_kernel(const ushort* __restrict__ Ag,
    const ushort* __restrict__ W1P, const ushort* __restrict__ W3P,
    const int* __restrict__ counts, const int* __restrict__ offs,
    ushort* __restrict__ hbuf){
  int r0 = blockIdx.y * 128;              // global packed row base
  if (r0 >= offs[NEXP]) return;
  int e = find_expert(offs, r0);
  int m0 = r0 - offs[e];
  int cnt = counts[e];
  if (m0 >= cnt) return;
  size_t rbase = (size_t)r0;
  const ushort* A0  = Ag + rbase*DIM;
  const ushort* W1e = W1P + (size_t)e*DIM*FF;
  const ushort* W3e = W3P + (size_t)e*DIM*FF;
  __shared__ ushort As[128*72];
  __shared__ ushort B1s[8192];
  __shared__ ushort B3s[8192];
  int tid = threadIdx.x;
  int lane = tid & 63, wid = tid >> 6;
  int wm = wid >> 1, wn = wid & 1;
  f32x4 z = {0.f, 0.f, 0.f, 0.f};
  f32x4 acc1[4][4], acc3[4][4];
#pragma unroll
  for (int i = 0; i < 4; ++i)
#pragma unroll
    for (int j = 0; j < 4; ++j){ acc1[i][j] = z; acc3[i][j] = z; }

  for (int kt = 0; kt < DIM/64; ++kt){
    int k0 = kt*64;
#pragma unroll
    for (int i = 0; i < 4; ++i){
      int id = tid + i*256;
      int row = id >> 3, kc = id & 7;
      short8 v = *(const short8*)(A0 + (size_t)row*DIM + k0 + kc*8);
      *(short8*)(As + row*72 + kc*8) = v;
    }
#pragma unroll
    for (int i = 0; i < 4; ++i){
      int bi = wid + i*4;
      int ktl = bi >> 3, ntl = bi & 7;
      size_t gb = ((size_t)(kt*2 + ktl)*(FF/16) + ((size_t)blockIdx.x*8 + ntl)) * 512;
      load_lds16(W1e + gb + lane*8, B1s + bi*512);
      load_lds16(W3e + gb + lane*8, B3s + bi*512);
    }
    __syncthreads();
#pragma unroll
    for (int ks = 0; ks < 2; ++ks){
      short8 a[4];
#pragma unroll
      for (int mf = 0; mf < 4; ++mf)
        a[mf] = *(const short8*)(As + (wm*64 + mf*16 + (lane&15))*72 + ks*32 + ((lane>>4)<<3));
#pragma unroll
      for (int nf = 0; nf < 4; ++nf){
        int bi = ks*8 + wn*4 + nf;
        short8 b1 = *(const short8*)(B1s + bi*512 + lane*8);
        short8 b3 = *(const short8*)(B3s + bi*512 + lane*8);
#pragma unroll
        for (int mf = 0; mf < 4; ++mf){
          acc1[mf][nf] = __builtin_amdgcn_mfma_f32_16x16x32_bf16(a[mf], b1, acc1[mf][nf], 0, 0, 0);
          acc3[mf][nf] = __builtin_amdgcn_mfma_f32_16x16x32_bf16(a[mf], b3, acc3[mf][nf], 0, 0, 0);
        }
      }
    }
    __syncthreads();
  }
  int colb = blockIdx.x*128 + wn*64 + (lane & 15);
  int rowb = wm*64 + ((lane >> 4) << 2);
#pragma unroll
  for (int mf = 0; mf < 4; ++mf){
#pragma unroll
    for (int r = 0; r < 4; ++r){
      int row = rowb + mf*16 + r;          // relative to m0
      if (m0 + row < cnt){
#pragma unroll
        for (int nf = 0; nf < 4; ++nf){
          float c1 = acc1[mf][nf][r], c3 = acc3[mf][nf][r];
          float h = c1 / (1.f + __expf(-c1)) * c3;
          hbuf[(rbase + row)*FF + colb + nf*16] = f2bf(h);
        }
      }
    }
  }
}

// GEMM2 fused: y[t] += w * (hbuf @ W2), atomic scatter (exactly 2 adds/elem, exact)
__global__ __launch_bounds__(256, 2) void gemm2f_kernel(const ushort* __restrict__ hbuf,
    const ushort* __restrict__ W2P, const int* __restrict__ counts,
    const int* __restrict__ offs, const int* __restrict__ etok,
    const float* __restrict__ ewt, float* __restrict__ y){
  int r0 = blockIdx.y * 128;
  if (r0 >= offs[NEXP]) return;
  int e = find_expert(offs, r0);
  int m0 = r0 - offs[e];
  int cnt = counts[e];
  if (m0 >= cnt) return;
  size_t rbase = (size_t)r0;
  const ushort* H0  = hbuf + rbase*FF;
  const ushort* W2e = W2P + (size_t)e*FF*DIM;
  __shared__ ushort As[128*72];
  __shared__ ushort Bs[8192];
  int tid = threadIdx.x;
  int lane = tid & 63, wid = tid >> 6;
  int wm = wid >> 1, wn = wid & 1;
  f32x4 z = {0.f, 0.f, 0.f, 0.f};
  f32x4 acc[4][4];
#pragma unroll
  for (int i = 0; i < 4; ++i)
#pragma unroll
    for (int j = 0; j < 4; ++j) acc[i][j] = z;

  for (int kt = 0; kt < FF/64; ++kt){
    int k0 = kt*64;
#pragma unroll
    for (int i = 0; i < 4; ++i){
      int id = tid + i*256;
      int row = id >> 3, kc = id & 7;
      short8 v = *(const short8*)(H0 + (size_t)row*FF + k0 + kc*8);
      *(short8*)(As + row*72 + kc*8) = v;
    }
#pragma unroll
    for (int i = 0; i < 4; ++i){
      int bi = wid + i*4;
      int ktl = bi >> 3, ntl = bi & 7;
      size_t gb = ((size_t)(kt*2 + ktl)*(DIM/16) + ((size_t)blockIdx.x*8 + ntl)) * 512;
      load_lds16(W2e + gb + lane*8, Bs + bi*512);
    }
    __syncthreads();
#pragma unroll
    for (int ks = 0; ks < 2; ++ks){
      short8 a[4];
#pragma unroll
      for (int mf = 0; mf < 4; ++mf)
        a[mf] = *(const short8*)(As + (wm*64 + mf*16 + (lane&15))*72 + ks*32 + ((lane>>4)<<3));
#pragma unroll
      for (int nf = 0; nf < 4; ++nf){
        int bi = ks*8 + wn*4 + nf;
        short8 b = *(const short8*)(Bs + bi*512 + lane*8);
#pragma unroll
        for (int mf = 0; mf < 4; ++mf)
          acc[mf][nf] = __builtin_amdgcn_mfma_f32_16x16x32_bf16(a[mf], b, acc[mf][nf], 0, 0, 0);
      }
    }
    __syncthreads();
  }
  int colb = blockIdx.x*128 + wn*64 + (lane & 15);
  int rowb = wm*64 + ((lane >> 4) << 2);
#pragma unroll
  for (int mf = 0; mf < 4; ++mf){
#pragma unroll
    for (int r = 0; r < 4; ++r){
      int row = rowb + mf*16 + r;          // relative to m0
      int er = m0 + row;
      if (er < cnt){
        int t = etok[e*TOK + er] & 0x7fffffff;
        float w = ewt[e*TOK + er];
        float* yr = y + (size_t)t*DIM;
#pragma unroll
        for (int nf = 0; nf < 4; ++nf)
          atomicAdd(&yr[colb + nf*16], acc[mf][nf][r] * w);
      }
    }
  }
}

// ======================= LEGACY per-expert fallback path =======================

__global__ void gather_pe(const float* __restrict__ x, const int* __restrict__ counts,
                          const int* __restrict__ etok, ushort* __restrict__ Ag, int e){
  int row = blockIdx.x;
  if (row >= counts[e]) return;
  int t = etok[e*TOK + row] & 0x7fffffff;
  int c = threadIdx.x;
  const float4* src = (const float4*)(x + (size_t)t*DIM + c*8);
  float4 a = src[0], b = src[1];
  ushort o[8] = { f2bf(a.x), f2bf(a.y), f2bf(a.z), f2bf(a.w),
                  f2bf(b.x), f2bf(b.y), f2bf(b.z), f2bf(b.w) };
  *(short8*)(Ag + (size_t)row*DIM + c*8) = *(const short8*)o;
}

__global__ void convw_pe(const float* __restrict__ W1, const float* __restrict__ W3,
                         const float* __restrict__ W2, ushort* __restrict__ W1P,
                         ushort* __restrict__ W3P, ushort* __restrict__ W2P, int e){
  const int NB = (DIM/32)*(FF/16);
  int lane = threadIdx.x & 63;
  int bo = blockIdx.x*4 + (threadIdx.x >> 6);
  const float* src; ushort* dst; int Nst;
  if (bo < NB)        { src = W1 + (size_t)e*DIM*FF; dst = W1P; Nst = FF; }
  else if (bo < 2*NB) { bo -= NB;   src = W3 + (size_t)e*DIM*FF; dst = W3P; Nst = FF; }
  else                { bo -= 2*NB; src = W2 + (size_t)e*FF*DIM; dst = W2P; Nst = DIM; }
  int ntn = Nst/16;
  int kt = bo / ntn, nt = bo - kt*ntn;
  int n  = nt*16 + (lane & 15);
  int k0 = kt*32 + ((lane >> 4) << 3);
  ushort o[8];
#pragma unroll
  for (int j = 0; j < 8; ++j) o[j] = f2bf(src[(size_t)(k0+j)*Nst + n]);
  *(short8*)(dst + (size_t)bo*512 + lane*8) = *(const short8*)o;
}

__global__ __launch_bounds__(256, 2) void gemm1_pe(const ushort* __restrict__ Ag,
    const ushort* __restrict__ W1P, const ushort* __restrict__ W3P,
    const int* __restrict__ counts, ushort* __restrict__ hbuf, int e){
  int cnt = counts[e];
  int m0 = blockIdx.y * 128;
  if (m0 >= cnt) return;
  int f0 = blockIdx.x * 128;
  __shared__ ushort As[128*72];
  __shared__ ushort B1s[8192];
  __shared__ ushort B3s[8192];
  int tid = threadIdx.x;
  int lane = tid & 63, wid = tid >> 6;
  int wm = wid >> 1, wn = wid & 1;
  f32x4 z = {0.f, 0.f, 0.f, 0.f};
  f32x4 acc1[4][4], acc3[4][4];
#pragma unroll
  for (int i = 0; i < 4; ++i)
#pragma unroll
    for (int j = 0; j < 4; ++j){ acc1[i][j] = z; acc3[i][j] = z; }
  for (int kt = 0; kt < DIM/64; ++kt){
    int k0 = kt*64;
#pragma unroll
    for (int i = 0; i < 4; ++i){
      int id = tid + i*256;
      int row = id >> 3, kc = id & 7;
      short8 v = *(const short8*)(Ag + (size_t)(m0+row)*DIM + k0 + kc*8);
      *(short8*)(As + row*72 + kc*8) = v;
    }
#pragma unroll
    for (int i = 0; i < 4; ++i){
      int bi = wid + i*4;
      int ktl = bi >> 3, ntl = bi & 7;
      size_t gb = ((size_t)(kt*2 + ktl)*(FF/16) + ((size_t)blockIdx.x*8 + ntl)) * 512;
      load_lds16(W1P + gb + lane*8, B1s + bi*512);
      load_lds16(W3P + gb + lane*8, B3s + bi*512);
    }
    __syncthreads();
#pragma unroll
    for (int ks = 0; ks < 2; ++ks){
      short8 a[4];
#pragma unroll
      for (int mf = 0; mf < 4; ++mf)
        a[mf] = *(const short8*)(As + (wm*64 + mf*16 + (lane&15))*72 + ks*32 + ((lane>>4)<<3));
#pragma unroll
      for (int nf = 0; nf < 4; ++nf){
        int bi = ks*8 + wn*4 + nf;
        short8 b1 = *(const short8*)(B1s + bi*512 + lane*8);
        short8 b3 = *(const short8*)(B3s + bi*512 + lane*8);
#pragma unroll
        for (int mf = 0; mf < 4; ++mf){
          acc1[mf][nf] = __builtin_amdgcn_mfma_f32_16x16x32_bf16(a[mf], b1, acc1[mf][nf], 0, 0, 0);
          acc3[mf][nf] = __builtin_amdgcn_mfma_f32_16x16x32_bf16(a[mf], b3, acc3[mf][nf], 0, 0, 0);
        }
      }
    }
    __syncthreads();
  }
  int colb = f0 + wn*64 + (lane & 15);
  int rowb = m0 + wm*64 + ((lane >> 4) << 2);
#pragma unroll
  for (int mf = 0; mf < 4; ++mf){
#pragma unroll
    for (int r = 0; r < 4; ++r){
      int row = rowb + mf*16 + r;
      if (row < cnt){
#pragma unroll
        for (int nf = 0; nf < 4; ++nf){
          float c1 = acc1[mf][nf][r], c3 = acc3[mf][nf][r];
          float h = c1 / (1.f + __expf(-c1)) * c3;
          hbuf[(size_t)row*FF + colb + nf*16] = f2bf(h);
        }
      }
    }
  }
}

__global__ __launch_bounds__(256, 2) void gemm2_pe(const ushort* __restrict__ hbuf,
    const ushort* __restrict__ W2P, const int* __restrict__ counts,
    const int* __restrict__ etok, const float* __restrict__ ewt,
    float* __restrict__ y, int e){
  int cnt = counts[e];
  int m0 = blockIdx.y * 128;
  if (m0 >= cnt) return;
  int d0 = blockIdx.x * 128;
  __shared__ ushort As[128*72];
  __shared__ ushort Bs[8192];
  int tid = threadIdx.x;
  int lane = tid & 63, wid = tid >> 6;
  int wm = wid >> 1, wn = wid & 1;
  f32x4 z = {0.f, 0.f, 0.f, 0.f};
  f32x4 acc[4][4];
#pragma unroll
  for (int i = 0; i < 4; ++i)
#pragma unroll
    for (int j = 0; j < 4; ++j) acc[i][j] = z;
  for (int kt = 0; kt < FF/64; ++kt){
    int k0 = kt*64;
#pragma unroll
    for (int i = 0; i < 4; ++i){
      int id = tid + i*256;
      int row = id >> 3, kc = id & 7;
      short8 v = *(const short8*)(hbuf + (size_t)(m0+row)*FF + k0 + kc*8);
      *(short8*)(As + row*72 + kc*8) = v;
    }
#pragma unroll
    for (int i = 0; i < 4; ++i){
      int bi = wid + i*4;
      int ktl = bi >> 3, ntl = bi & 7;
      size_t gb = ((size_t)(kt*2 + ktl)*(DIM/16) + ((size_t)blockIdx.x*8 + ntl)) * 512;
      load_lds16(W2P + gb + lane*8, Bs + bi*512);
    }
    __syncthreads();
#pragma unroll
    for (int ks = 0; ks < 2; ++ks){
      short8 a[4];
#pragma unroll
      for (int mf = 0; mf < 4; ++mf)
        a[mf] = *(const short8*)(As + (wm*64 + mf*16 + (lane&15))*72 + ks*32 + ((lane>>4)<<3));
#pragma unroll
      for (int nf = 0; nf < 4; ++nf){
        int bi = ks*8 + wn*4 + nf;
        short8 b = *(const short8*)(Bs + bi*512 + lane*8);
#pragma unroll
        for (int mf = 0; mf < 4; ++mf)
          acc[mf][nf] = __builtin_amdgcn_mfma_f32_16x16x32_bf16(a[mf], b, acc[mf][nf], 0, 0, 0);
      }
    }
    __syncthreads();
  }
  int colb = d0 + wn*64 + (lane & 15);
  int rowb = m0 + wm*64 + ((lane >> 4) << 2);
#pragma unroll
  for (int mf = 0; mf < 4; ++mf){
#pragma unroll
    for (int r = 0; r < 4; ++r){
      int row = rowb + mf*16 + r;
      if (row < cnt){
        int v = etok[e*TOK + row];
        int t = v & 0x7fffffff;
        float w = ewt[e*TOK + row];
        bool first = (v < 0);
        float* yr = y + (size_t)t*DIM;
#pragma unroll
        for (int nf = 0; nf < 4; ++nf){
          float val = acc[mf][nf][r] * w;
          int col = colb + nf*16;
          if (first) yr[col] = val;
          else       yr[col] += val;
        }
      }
    }
  }
}

extern "C" void kernel_launch(void* const* d_in, const int* in_sizes, int n_in,
                              void* d_out, int out_size, void* d_ws, size_t ws_size,
                              hipStream_t stream){
  const float* x  = (const float*)d_in[0];
  const float* Wg = (const float*)d_in[1];
  const float* W1 = (const float*)d_in[2];
  const float* W3 = (const float*)d_in[3];
  const float* W2 = (const float*)d_in[4];
  float* y      = (float*)d_out;
  float* logits = y + (size_t)TOK*DIM;

  char* ws = (char*)d_ws;
  size_t off = 0;
  auto alloc = [&](size_t b)->char*{ char* p = ws + off; off += (b + 255) & ~(size_t)255; return p; };

  // fused path needs: small bufs + packed Ag/hbuf + all-expert bf16 weights
  const size_t FUSED_NEED =
      256 + 256 + (size_t)NEXP*TOK*4 + (size_t)NEXP*TOK*4 + (size_t)2*TOK*4 +
      (size_t)MAXROWS*DIM*2 + (size_t)MAXROWS*FF*2 +
      3*(size_t)NEXP*DIM*FF*2 + 65536;

  if (ws_size >= FUSED_NEED){
    int*    counts = (int*)   alloc(NEXP*sizeof(int));
    int*    offs   = (int*)   alloc((NEXP+1)*sizeof(int));
    int*    etok   = (int*)   alloc((size_t)NEXP*TOK*sizeof(int));
    float*  ewt    = (float*) alloc((size_t)NEXP*TOK*sizeof(float));
    int*    eslot  = (int*)   alloc((size_t)2*TOK*sizeof(int));
    ushort* Ag     = (ushort*)alloc((size_t)MAXROWS*DIM*2);     // 37.7 MB
    ushort* hbuf   = (ushort*)alloc((size_t)MAXROWS*FF*2);      // 75.5 MB
    ushort* W1P    = (ushort*)alloc((size_t)NEXP*DIM*FF*2);     // 134 MB
    ushort* W3P    = (ushort*)alloc((size_t)NEXP*DIM*FF*2);     // 134 MB
    ushort* W2P    = (ushort*)alloc((size_t)NEXP*FF*DIM*2);     // 134 MB

    hipMemsetAsync(counts, 0, NEXP*sizeof(int), stream);
    hipMemsetAsync(y, 0, (size_t)TOK*DIM*sizeof(float), stream);
    router_kernel<<<TOK/4, 256, 0, stream>>>(x, Wg, logits, counts, etok, ewt, eslot);
    offsets_kernel<<<1, 64, 0, stream>>>(counts, offs);
    gatherf_kernel<<<2*TOK, 256, 0, stream>>>(x, offs, eslot, Ag);
    convwf_kernel<<<3*NEXP*(DIM/32)*(FF/16)/4, 256, 0, stream>>>(W1, W3, W2, W1P, W3P, W2P);
    gemm1f_kernel<<<dim3(FF/128, MAXROWS/128), 256, 0, stream>>>(Ag, W1P, W3P, counts, offs, hbuf);
    gemm2f_kernel<<<dim3(DIM/128, MAXROWS/128), 256, 0, stream>>>(hbuf, W2P, counts, offs, etok, ewt, y);
  } else {
    // legacy per-expert path (verbatim previous kernel)
    int*    counts = (int*)   alloc(NEXP*sizeof(int));
    int*    etok   = (int*)   alloc((size_t)NEXP*TOK*sizeof(int));
    float*  ewt    = (float*) alloc((size_t)NEXP*TOK*sizeof(float));
    int*    eslot  = (int*)   alloc((size_t)2*TOK*sizeof(int));
    ushort* Ag     = (ushort*)alloc((size_t)TOK*DIM*2);
    ushort* hbuf   = (ushort*)alloc((size_t)TOK*FF*2);
    ushort* W1P    = (ushort*)alloc((size_t)DIM*FF*2);
    ushort* W3P    = (ushort*)alloc((size_t)DIM*FF*2);
    ushort* W2P    = (ushort*)alloc((size_t)FF*DIM*2);

    hipMemsetAsync(counts, 0, NEXP*sizeof(int), stream);
    router_kernel<<<TOK/4, 256, 0, stream>>>(x, Wg, logits, counts, etok, ewt, eslot);
    for (int e = 0; e < NEXP; ++e){
      gather_pe<<<TOK, 256, 0, stream>>>(x, counts, etok, Ag, e);
      convw_pe<<<3*(DIM/32)*(FF/16)/4, 256, 0, stream>>>(W1, W3, W2, W1P, W3P, W2P, e);
      gemm1_pe<<<dim3(FF/128, TOK/128), 256, 0, stream>>>(Ag, W1P, W3P, counts, hbuf, e);
      gemm2_pe<<<dim3(DIM/128, TOK/128), 256, 0, stream>>>(hbuf, W2P, counts, etok, ewt, y, e);
    }
  }
}